// Round 6
// baseline (2581.841 us; speedup 1.0000x reference)
//
#include <hip/hip_runtime.h>
#include <hip/hip_bf16.h>
#include <math.h>

#define SEQ    1024
#define EMB    512
#define HID    512
#define G4     2048   // 4*HID
#define NSCAN  16     // scan blocks
#define UPB    32     // hidden units per scan block
#define NSLOT  4      // rotating h slots (WAR-safe at distance 4)

typedef unsigned long long u64;

// ---------------------------------------------------------------------------
// Phase A: x_gates[t][r] = dot(emb[tok[t]], w_ih[r]) + b_ih[r] + b_hh[r]
// R1-proven 64x64 tile, K-chunks of 64, 4x4 micro-tile per thread.
// ---------------------------------------------------------------------------
__global__ __launch_bounds__(256) void xgates_kernel(
    const int* __restrict__ tok, const float* __restrict__ emb,
    const float* __restrict__ w_ih, const float* __restrict__ b_ih,
    const float* __restrict__ b_hh, float* __restrict__ xg)
{
  __shared__ float xs[64][68];
  __shared__ float wsh[64][68];
  __shared__ int   tok_s[64];

  const int tid = threadIdx.x;
  const int r0  = (int)blockIdx.x * 64;
  const int t0  = (int)blockIdx.y * 64;

  if (tid < 64) tok_s[tid] = tok[t0 + tid];
  __syncthreads();

  const int tx = tid & 15;
  const int ty = tid >> 4;

  float acc[4][4];
#pragma unroll
  for (int i = 0; i < 4; ++i)
#pragma unroll
    for (int j = 0; j < 4; ++j) acc[i][j] = 0.f;

  for (int kc = 0; kc < EMB; kc += 64) {
#pragma unroll
    for (int it = 0; it < 4; ++it) {
      int id  = it * 256 + tid;
      int row = id >> 4;
      int c4  = id & 15;
      *(float4*)&xs[row][c4 * 4] =
          *(const float4*)(emb + (size_t)tok_s[row] * EMB + kc + c4 * 4);
      *(float4*)&wsh[row][c4 * 4] =
          *(const float4*)(w_ih + (size_t)(r0 + row) * EMB + kc + c4 * 4);
    }
    __syncthreads();

#pragma unroll
    for (int k4 = 0; k4 < 16; ++k4) {
      float4 xv[4], wv[4];
#pragma unroll
      for (int i = 0; i < 4; ++i) xv[i] = *(const float4*)&xs[ty * 4 + i][k4 * 4];
#pragma unroll
      for (int j = 0; j < 4; ++j) wv[j] = *(const float4*)&wsh[tx * 4 + j][k4 * 4];
#pragma unroll
      for (int i = 0; i < 4; ++i)
#pragma unroll
        for (int j = 0; j < 4; ++j) {
          acc[i][j] += xv[i].x * wv[j].x + xv[i].y * wv[j].y
                     + xv[i].z * wv[j].z + xv[i].w * wv[j].w;
        }
    }
    __syncthreads();
  }

  const int rbase = r0 + tx * 4;
  float bias[4];
#pragma unroll
  for (int j = 0; j < 4; ++j) bias[j] = b_ih[rbase + j] + b_hh[rbase + j];

#pragma unroll
  for (int i = 0; i < 4; ++i) {
    int t = t0 + ty * 4 + i;
    float4 o;
    o.x = acc[i][0] + bias[0];
    o.y = acc[i][1] + bias[1];
    o.z = acc[i][2] + bias[2];
    o.w = acc[i][3] + bias[3];
    *(float4*)(xg + (size_t)t * G4 + rbase) = o;
  }
}

// ---------------------------------------------------------------------------
// Phase B+C: LSTM scan (16 persistent blocks x 512 threads) + fused head.
// Exchange: u64 (tag<<32|f32) words, relaxed agent atomics (R2-proven).
// Per step: poll own word -> LDS (own-wave region, no barrier) -> partial
// dots (2 rows/thread) -> ONE barrier -> ALL waves reduce 4 units each
// (swizzled conflict-free LDS reads) -> lanes 0-3 of each wave do gate math
// and store 4 words. Tail parallelized 8x vs R2 (was wave0-serial).
// ---------------------------------------------------------------------------
__global__ __launch_bounds__(512) void lstm_scan_kernel(
    const float* __restrict__ xg, const float* __restrict__ w_hh,
    const float* __restrict__ attn_w, const float* __restrict__ attn_b,
    float* __restrict__ out, u64* hslot)
{
  __shared__ float h_lds[512];
  __shared__ float pl[2][1024];     // partials: [w*128 + q*32 + ((u+8q)&31)]
  __shared__ float redh[8];
  __shared__ float avals[4];

  const int tid = threadIdx.x;
  const int b   = blockIdx.x;        // 0..15: owns units [32b, 32b+32)
  const int w   = tid >> 6;          // wave = k-segment [64w, 64w+64)
  const int l   = tid & 63;
  const int u   = l & 31;            // unit_local for partial rows
  const int qh  = l >> 5;            // 0/1
  // this thread's two gate rows: q=qh and q=qh+2
  const int R0 = qh * HID + b * UPB + u;
  const int R1 = (2 + qh) * HID + b * UPB + u;
  // partial write slots (2-way bank alias = free per m136)
  const int wr0 = w * 128 + qh * 32       + ((u + 8 * qh) & 31);
  const int wr1 = w * 128 + (qh + 2) * 32 + ((u + 8 * (qh + 2)) & 31);

  // reduction role (lanes 0..15 of every wave): unit Ur = 4w + (l>>2), gate l&3
  const int qr  = l & 3;
  const int Ur  = 4 * w + (l >> 2);
  const int xrow = qr * HID + b * UPB + Ur;             // row in xg
  const int rcol = qr * 32 + ((Ur + 8 * qr) & 31);      // column in pl

  // 128 w_hh weights -> VGPRs
  float w0r[64], w1r[64];
  {
    const float4* p0 = (const float4*)(w_hh + (size_t)R0 * HID + w * 64);
    const float4* p1 = (const float4*)(w_hh + (size_t)R1 * HID + w * 64);
#pragma unroll
    for (int k4 = 0; k4 < 16; ++k4) {
      float4 a = p0[k4], c = p1[k4];
      w0r[4 * k4 + 0] = a.x; w0r[4 * k4 + 1] = a.y;
      w0r[4 * k4 + 2] = a.z; w0r[4 * k4 + 3] = a.w;
      w1r[4 * k4 + 0] = c.x; w1r[4 * k4 + 1] = c.y;
      w1r[4 * k4 + 2] = c.z; w1r[4 * k4 + 3] = c.w;
    }
  }

  float c_reg = 0.f;                        // unit state (lanes 0..3 per wave)
  float xqv = (l < 16) ? xg[xrow] : 0.f;    // x_gates[0][xrow] (xg is ready)

  for (int t = 0; t < SEQ; ++t) {
    // Poll own h word (tag<<32 | payload) — relaxed agent atomic, R2-proven.
    const u64* src = hslot + (size_t)(t & (NSLOT - 1)) * HID + tid;
    u64 word;
    do {
      word = __hip_atomic_load(src, __ATOMIC_RELAXED, __HIP_MEMORY_SCOPE_AGENT);
    } while ((unsigned)(word >> 32) != (unsigned)t);
    h_lds[tid] = __uint_as_float((unsigned)word);
    // wave w reads only h_lds[64w..64w+64) written by its own lanes.

    const float* hb = &h_lds[w * 64];
    float p0 = 0.f, p1 = 0.f, q0 = 0.f, q1 = 0.f;
#pragma unroll
    for (int k4 = 0; k4 < 16; ++k4) {
      float4 hv = *(const float4*)&hb[k4 * 4];
      p0 += w0r[4 * k4 + 0] * hv.x + w0r[4 * k4 + 1] * hv.y;
      p1 += w0r[4 * k4 + 2] * hv.z + w0r[4 * k4 + 3] * hv.w;
      q0 += w1r[4 * k4 + 0] * hv.x + w1r[4 * k4 + 1] * hv.y;
      q1 += w1r[4 * k4 + 2] * hv.z + w1r[4 * k4 + 3] * hv.w;
    }
    float* pc = pl[t & 1];
    pc[wr0] = p0 + p1;
    pc[wr1] = q0 + q1;
    __syncthreads();   // the only barrier per step

    // All 8 waves: lanes 0..15 reduce one (gate,unit) row each.
    float gv = 0.f;
    if (l < 16) {
      const float* pp = pl[t & 1];
      float s0 = pp[0 * 128 + rcol] + pp[1 * 128 + rcol];
      float s1 = pp[2 * 128 + rcol] + pp[3 * 128 + rcol];
      float s2 = pp[4 * 128 + rcol] + pp[5 * 128 + rcol];
      float s3 = pp[6 * 128 + rcol] + pp[7 * 128 + rcol];
      gv = (s0 + s1) + (s2 + s3) + xqv;
      // prefetch next step's xq (independent -> latency hidden)
      int tn = (t + 1 < SEQ) ? (t + 1) : (SEQ - 1);
      xqv = xg[(size_t)tn * G4 + xrow];
    }
    // gather 4 gates of unit (l&3) onto lanes 0..3 (full-wave shfl)
    float gi = __shfl(gv, 4 * (l & 3) + 0, 64);
    float gf = __shfl(gv, 4 * (l & 3) + 1, 64);
    float gg = __shfl(gv, 4 * (l & 3) + 2, 64);
    float go = __shfl(gv, 4 * (l & 3) + 3, 64);

    if (l < 4) {
      const float LOG2E = 1.442695041f;
      float i_ = 1.f / (1.f + __builtin_exp2f(-LOG2E * gi));
      float f_ = 1.f / (1.f + __builtin_exp2f(-LOG2E * gf));
      float g_ = 2.f / (1.f + __builtin_exp2f(-2.f * LOG2E * gg)) - 1.f;
      float o_ = 1.f / (1.f + __builtin_exp2f(-LOG2E * go));
      c_reg = f_ * c_reg + i_ * g_;
      float hv = o_ * (2.f / (1.f + __builtin_exp2f(-2.f * LOG2E * c_reg)) - 1.f);
      u64 outw = ((u64)(unsigned)(t + 1) << 32) | (u64)__float_as_uint(hv);
      __hip_atomic_store(
          hslot + (size_t)((t + 1) & (NSLOT - 1)) * HID + b * UPB + 4 * w + l,
          outw, __ATOMIC_RELAXED, __HIP_MEMORY_SCOPE_AGENT);
    }
  }

  // ============================ HEAD PHASE ============================
  // h^1024 in slot (1024 & 3) == 0 with tag 1024. Block b -> rows 4b..4b+3.
  {
    const u64* src = hslot + tid;
    u64 word;
    do {
      word = __hip_atomic_load(src, __ATOMIC_RELAXED, __HIP_MEMORY_SCOPE_AGENT);
    } while ((unsigned)(word >> 32) != (unsigned)SEQ);
    h_lds[tid] = __uint_as_float((unsigned)word);
    __syncthreads();

    const int row  = 4 * b + (w & 3);
    const int half = w >> 2;
    const int k0   = half * 256 + l * 4;
    float4 wv = *(const float4*)(attn_w + (size_t)row * HID + k0);
    float4 hv = *(const float4*)&h_lds[k0];
    float p = wv.x * hv.x + wv.y * hv.y + wv.z * hv.z + wv.w * hv.w;
#pragma unroll
    for (int off = 1; off < 64; off <<= 1) p += __shfl_xor(p, off, 64);
    if (l == 0) redh[w] = p;
    __syncthreads();
    if (tid < 4) {
      float s = redh[tid] + redh[tid + 4] + attn_b[4 * b + tid];
      avals[tid] = 1.f / (1.f + __expf(-s));
    }
    __syncthreads();

    const int rr = tid >> 7, kk = tid & 127;
    float a = avals[rr];
    float4 av = make_float4(a, a, a, a);
    float4* op = (float4*)(out + (size_t)(4 * b + rr) * 1024);
    op[kk * 2]     = av;
    op[kk * 2 + 1] = av;
    if (b == 0) out[65536 + tid] = h_lds[tid];   // x_instr_rep = h
  }
}

// ---------------------------------------------------------------------------
extern "C" void kernel_launch(void* const* d_in, const int* in_sizes, int n_in,
                              void* d_out, int out_size, void* d_ws, size_t ws_size,
                              hipStream_t stream) {
  const int*   tok    = (const int*)  d_in[0];
  const float* emb    = (const float*)d_in[1];
  const float* w_ih   = (const float*)d_in[2];
  const float* w_hh   = (const float*)d_in[3];
  const float* b_ih   = (const float*)d_in[4];
  const float* b_hh   = (const float*)d_in[5];
  const float* attn_w = (const float*)d_in[6];
  const float* attn_b = (const float*)d_in[7];
  float* out = (float*)d_out;

  float* xg    = (float*)d_ws;                                  // 8 MB
  u64*   hslot = (u64*)((char*)d_ws + (size_t)SEQ * G4 * 4);    // 16 KB

  // ws is poisoned 0xAA before every launch: zero h slots (tag 0 == h^0 = 0).
  hipMemsetAsync(hslot, 0, NSLOT * HID * sizeof(u64), stream);

  dim3 gA(G4 / 64, SEQ / 64);   // 32 x 16 tiles
  xgates_kernel<<<gA, 256, 0, stream>>>(tok, emb, w_ih, b_ih, b_hh, xg);
  lstm_scan_kernel<<<NSCAN, 512, 0, stream>>>(xg, w_hh, attn_w, attn_b, out, hslot);
}